// Round 1
// 761.246 us; speedup vs baseline: 1.0275x; 1.0275x over previous
//
#include <hip/hip_runtime.h>

typedef __bf16 bf16;
typedef __bf16 bf16x8 __attribute__((ext_vector_type(8)));
typedef float f32x4 __attribute__((ext_vector_type(4)));

#define N_DSTN 8192
#define TT 16
#define HROW 72            // shorts per h row (64 + 8 pad); 144B row keeps 16B align for b128
#define HBUF (32 * HROW)   // one parity buffer, in shorts

__device__ __forceinline__ f32x4 MFMA(bf16x8 a, bf16x8 b, f32x4 c) {
    return __builtin_amdgcn_mfma_f32_16x16x32_bf16(a, b, c, 0, 0, 0);
}
__device__ __forceinline__ float ldf(const void* p, long i, bool isb) {
    return isb ? (float)((const bf16*)p)[i] : ((const float*)p)[i];
}
__device__ __forceinline__ bf16x8 zero8() {
    bf16x8 z;
    #pragma unroll
    for (int i = 0; i < 8; i++) z[i] = (bf16)0.0f;
    return z;
}
// 8 consecutive elements as bf16x8; i must be a multiple of 4
__device__ __forceinline__ bf16x8 ld8v(const void* p, long i, bool isb) {
    if (isb) {
        return *reinterpret_cast<const bf16x8*>((const bf16*)p + i);
    } else {
        const float* f = (const float*)p + i;
        float4 u = *reinterpret_cast<const float4*>(f);
        float4 v = *reinterpret_cast<const float4*>(f + 4);
        bf16x8 r;
        r[0] = (bf16)u.x; r[1] = (bf16)u.y; r[2] = (bf16)u.z; r[3] = (bf16)u.w;
        r[4] = (bf16)v.x; r[5] = (bf16)v.y; r[6] = (bf16)v.z; r[7] = (bf16)v.w;
        return r;
    }
}
// scaled load: rounds (s*w) to bf16 — single rounding when source is f32
__device__ __forceinline__ bf16x8 ld8vs(const void* p, long i, bool isb, float s) {
    bf16x8 r;
    if (isb) {
        bf16x8 v = *reinterpret_cast<const bf16x8*>((const bf16*)p + i);
        #pragma unroll
        for (int j = 0; j < 8; j++) r[j] = (bf16)((float)v[j] * s);
    } else {
        const float* f = (const float*)p + i;
        float4 u = *reinterpret_cast<const float4*>(f);
        float4 v = *reinterpret_cast<const float4*>(f + 4);
        r[0] = (bf16)(u.x * s); r[1] = (bf16)(u.y * s); r[2] = (bf16)(u.z * s); r[3] = (bf16)(u.w * s);
        r[4] = (bf16)(v.x * s); r[5] = (bf16)(v.y * s); r[6] = (bf16)(v.z * s); r[7] = (bf16)(v.w * s);
    }
    return r;
}

extern "C" __global__ void __launch_bounds__(512, 4)
gtea_fused(const void* __restrict__ node_features,
           const void* __restrict__ edge_feats,
           const void* __restrict__ e_times,
           const int*  __restrict__ e_len,
           const int*  __restrict__ edge_src,
           const void* __restrict__ t2v_w,
           const void* __restrict__ t2v_b,
           const void* __restrict__ t2v_w0,
           const void* __restrict__ t2v_b0,
           const void* __restrict__ Wih_e,
           const void* __restrict__ Whh_e,
           const void* __restrict__ bih_e,
           const void* __restrict__ bhh_e,
           const void* __restrict__ Wih_a,
           const void* __restrict__ Whh_a,
           const void* __restrict__ bih_a,
           const void* __restrict__ bhh_a,
           const void* __restrict__ attn_w,
           const void* __restrict__ edge_out_W,
           const void* __restrict__ edge_out_b,
           const void* __restrict__ node_W,
           const void* __restrict__ node_b,
           void* __restrict__ outp)
{
    // LDS total = 40772 B (rounds to 40832 <= 40960 -> 4 blocks/CU resource-legal)
    __shared__ __align__(16) bf16 habuf[2][2][HBUF];   // [L][parity]  18432 B
    __shared__ __align__(16) bf16 hsrc[32 * HROW];     // 4608 B
    __shared__ __align__(16) bf16 featb[TT * 32 * 8];  // 8192 B
    __shared__ __align__(16) bf16 tb[TT * 32 * 8];     // 8192 B
    __shared__ float t2w[8], t2b[8];
    __shared__ float attn_f[64];
    __shared__ float vbuf[128];
    __shared__ float scores_sh[32], alpha_sh[32];
    __shared__ int   lens_sh[32], idx_sh[32];
    __shared__ int   isb_sh;

    const int tid = threadIdx.x;
    const int w   = tid >> 6;
    const int l   = tid & 63;
    const int l15 = l & 15;
    const int q   = l >> 4;
    const int L   = w >> 2;          // 0: lstm_e, 1: lstm_a
    const int w4  = w & 3;
    const int u16 = w4 * 16 + l15;

    const int d  = blockIdx.x;
    const int e0 = d * 32;

    // ---- dtype sniff ----
    if (tid < 64) {
        const unsigned short* u = (const unsigned short*)e_times;
        unsigned short a = u[tid * 2], b = u[tid * 2 + 1];
        bool ok = (a <= 0x3F80u) && (b <= 0x3F80u);
        unsigned long long m = __ballot(ok);
        if (tid == 0) isb_sh = (m == ~0ULL) ? 1 : 0;
    }
    // ---- in-wave length sort (wave 0, no LDS scratch) ----
    if (tid < 32) {
        int lj = e_len[e0 + tid];
        int rank = 0;
        for (int i = 0; i < 32; i++) {
            int li = __shfl(lj, i);
            rank += (li > lj) || (li == lj && i < tid);
        }
        int mt = rank >> 4, kp = rank & 15;
        int slot = mt * 16 + (kp & 3) * 4 + (kp >> 2);
        idx_sh[slot]  = tid;
        lens_sh[slot] = lj;
    }
    __syncthreads();
    const bool isb = (isb_sh != 0);

    // ---- S0: params, h_dst, habuf zero ----
    if (tid < 7)  { t2w[tid] = ldf(t2v_w, tid, isb); t2b[tid] = ldf(t2v_b, tid, isb); }
    if (tid == 7) { t2w[7] = ldf(t2v_w0, 0, isb); t2b[7] = ldf(t2v_b0, 0, isb); }
    if (tid < 64) attn_f[tid] = ldf(attn_w, tid, isb);
    if (tid < 64) vbuf[tid] = ldf(node_features, (long)d * 64 + tid, isb);
    {
        unsigned int* hz = reinterpret_cast<unsigned int*>(&habuf[0][0][0]);
        for (int i = tid; i < 2 * 2 * HBUF / 2; i += 512) hz[i] = 0u;
    }
    __syncthreads();

    // ---- S2: edge staging + pre-scaled weights ----
    int gm0[4], gm1[4];
    #pragma unroll
    for (int r = 0; r < 4; r++) {
        gm0[r] = __builtin_amdgcn_readfirstlane(lens_sh[r]);
        gm1[r] = __builtin_amdgcn_readfirstlane(lens_sh[16 + r]);
    }
    const int tmax = gm0[0], mtmax1 = gm1[0];

    unsigned lp = 0;
    #pragma unroll
    for (int mt = 0; mt < 2; mt++)
        #pragma unroll
        for (int r = 0; r < 4; r++)
            lp |= (unsigned)(lens_sh[mt * 16 + q * 4 + r] - 1) << ((mt * 4 + r) * 4);

    if (tid < 256) {
        int s = tid >> 3, c8 = tid & 7;
        int src = edge_src[e0 + idx_sh[s]];
        *reinterpret_cast<bf16x8*>(&hsrc[s * HROW + c8 * 8]) =
            ld8v(node_features, (long)src * 64 + c8 * 8, isb);
    }
    {
        int s = tid >> 4, t = tid & 15;
        int j = idx_sh[s];
        long base = ((long)(e0 + j) * TT + t) * 8;
        *reinterpret_cast<bf16x8*>(&featb[(t * 32 + s) * 8]) = ld8v(edge_feats, base, isb);
        float tau = ldf(e_times, (long)(e0 + j) * TT + t, isb);
        bf16x8 te;
        #pragma unroll
        for (int i = 0; i < 7; i++) te[i] = (bf16)__sinf(tau * t2w[i] + t2b[i]);
        te[7] = (bf16)(tau * t2w[7] + t2b[7]);
        *reinterpret_cast<bf16x8*>(&tb[(t * 32 + s) * 8]) = te;
    }

    const void* Whh = L ? Whh_a : Whh_e;
    const void* Wih = L ? Wih_a : Wih_e;
    const void* bih = L ? bih_a : bih_e;
    const void* bhh = L ? bhh_a : bhh_e;
    // fold the exp2 argument scale into weights/bias: i,f,o -> -1/ln2 ; g -> +2/ln2
    bf16x8 Bh[4][2], Bx[4];
    float  bias[4];
    #pragma unroll
    for (int j = 0; j < 4; j++) {
        const float gs = (j == 2) ? 2.88539008f : -1.44269504f;
        int n = 64 * j + u16;
        Bh[j][0] = ld8vs(Whh, (long)n * 64 + q * 8, isb, gs);
        Bh[j][1] = ld8vs(Whh, (long)n * 64 + 32 + q * 8, isb, gs);
        Bx[j] = (q < 2) ? ld8vs(Wih, (long)n * 16 + q * 8, isb, gs) : zero8();
        bias[j] = (ldf(bih, n, isb) + ldf(bhh, n, isb)) * gs;
    }

    float c[2][4];
    #pragma unroll
    for (int mt = 0; mt < 2; mt++)
        #pragma unroll
        for (int r = 0; r < 4; r++) c[mt][r] = 0.0f;

    __syncthreads();

    // ---- recurrent loop: double-buffered h, 1 barrier/step ----
    bf16* hb_base = &habuf[L][0][0];
    const int rd_off = l15 * HROW + q * 8;          // per-lane read base within mt slab
    const int wr_off = (q * 4) * HROW + u16;        // per-lane write base within mt slab

    for (int t = 0; t < tmax; t++) {
        const bf16* hbR = hb_base + (t & 1) * HBUF;
        bf16*       hbW = hb_base + ((t + 1) & 1) * HBUF;

        auto do_mt = [&](int mt) {
            const bf16* hr = hbR + mt * (16 * HROW) + rd_off;
            bf16x8 ah0 = *reinterpret_cast<const bf16x8*>(hr);
            bf16x8 ah1 = *reinterpret_cast<const bf16x8*>(hr + 32);
            bf16x8 xa;
            if (q < 2) {
                const bf16* xp = (q == 0 ? featb : tb) + (t * 32 + mt * 16 + l15) * 8;
                xa = *reinterpret_cast<const bf16x8*>(xp);
            } else {
                xa = zero8();
            }
            f32x4 D[4];
            #pragma unroll
            for (int j = 0; j < 4; j++) {
                f32x4 acc = {bias[j], bias[j], bias[j], bias[j]};
                acc = MFMA(ah0, Bh[j][0], acc);
                acc = MFMA(ah1, Bh[j][1], acc);
                acc = MFMA(xa,  Bx[j],    acc);
                D[j] = acc;
            }
            bf16* hw = hbW + mt * (16 * HROW) + wr_off;
            #pragma unroll
            for (int r = 0; r < 4; r++) {
                int gmax = mt ? gm1[r] : gm0[r];
                if (t < gmax) {
                    int lm1 = (int)((lp >> ((mt * 4 + r) * 4)) & 15u);
                    if (t <= lm1) {
                        // gates pre-scaled: gi,gf,go = -x/ln2 ; gg = +2x/ln2
                        float gi = D[0][r], gf = D[1][r];
                        float gg = D[2][r], go = D[3][r];
                        float ei = __builtin_amdgcn_exp2f(gi);
                        float ef = __builtin_amdgcn_exp2f(gf);
                        float eg = __builtin_amdgcn_exp2f(gg);
                        float di = 1.0f + ei, dfv = 1.0f + ef, dg = 1.0f + eg;
                        float m1 = di * dg;
                        float R1 = __builtin_amdgcn_rcpf(m1 * dfv);
                        // sigma(f)*c + sigma(i)*tanh(g) with one rcp
                        float cn = (m1 * R1) * c[mt][r] + (eg - 1.0f) * (dfv * R1);
                        c[mt][r] = cn;
                        float eo = __builtin_amdgcn_exp2f(go);
                        float ec = __builtin_amdgcn_exp2f(2.88539008f * cn);
                        // sigma(o)*tanh(cn) = (ec-1) * rcp(do*dc)  — one rcp, no recovery
                        float R2 = __builtin_amdgcn_rcpf((1.0f + eo) * (1.0f + ec));
                        float hn = (ec - 1.0f) * R2;
                        hw[r * HROW] = (bf16)hn;
                    }
                }
            }
        };
        do_mt(0);
        if (t < mtmax1) do_mt(1);
        __syncthreads();
    }

    // ---- epilogue ----
    if (tid < 256) {   // attention scores
        int s = tid >> 3, c8 = tid & 7;
        const bf16* ha = &habuf[1][lens_sh[s] & 1][s * HROW];
        float p = 0.0f;
        #pragma unroll
        for (int i = 0; i < 8; i++)
            p += (float)ha[c8 * 8 + i] * attn_f[c8 * 8 + i];
        p += __shfl_xor(p, 1);
        p += __shfl_xor(p, 2);
        p += __shfl_xor(p, 4);
        if (c8 == 0) scores_sh[s] = (p > 0.0f) ? p : 0.01f * p;
    }
    float mval[2][4];
    if (tid < 256) {   // m = relu([h_src | h_e] @ edge_out_W^T + b)
        bf16x8 Bw[4];
        #pragma unroll
        for (int ks = 0; ks < 4; ks++)
            Bw[ks] = ld8v(edge_out_W, (long)u16 * 128 + ks * 32 + q * 8, isb);
        float mb = ldf(edge_out_b, u16, isb);
        #pragma unroll
        for (int mt = 0; mt < 2; mt++) {
            int s = mt * 16 + l15;
            const bf16* hs = &hsrc[s * HROW];
            const bf16* he = &habuf[0][lens_sh[s] & 1][s * HROW];
            bf16x8 a0 = *reinterpret_cast<const bf16x8*>(hs + q * 8);
            bf16x8 a1 = *reinterpret_cast<const bf16x8*>(hs + 32 + q * 8);
            bf16x8 a2 = *reinterpret_cast<const bf16x8*>(he + q * 8);
            bf16x8 a3 = *reinterpret_cast<const bf16x8*>(he + 32 + q * 8);
            f32x4 acc = {mb, mb, mb, mb};
            acc = MFMA(a0, Bw[0], acc);
            acc = MFMA(a1, Bw[1], acc);
            acc = MFMA(a2, Bw[2], acc);
            acc = MFMA(a3, Bw[3], acc);
            #pragma unroll
            for (int r = 0; r < 4; r++) mval[mt][r] = fmaxf(acc[r], 0.0f);
        }
    }
    __syncthreads();

    if (tid < 64) {   // sparsemax (reference-exact)
        float z = (tid < 32) ? scores_sh[tid] : -3.0e38f;
        float zm = z;
        #pragma unroll
        for (int m = 32; m >= 1; m >>= 1) zm = fmaxf(zm, __shfl_xor(zm, m));
        z -= zm;
        int cnt = 0; float sb = 0.0f;
        for (int i = 0; i < 32; i++) {
            float zi = __shfl(z, i);
            bool before = (zi > z) || (zi == z && i < tid);
            if (before) { cnt++; sb += zi; }
        }
        float r = (float)(cnt + 1);
        float S = sb + z;
        bool isgt = (tid < 32) && (1.0f + r * z > S);
        float kf  = isgt ? r : 0.0f;
        float sgt = isgt ? z : 0.0f;
        #pragma unroll
        for (int m = 32; m >= 1; m >>= 1) kf = fmaxf(kf, __shfl_xor(kf, m));
        #pragma unroll
        for (int m = 32; m >= 1; m >>= 1) sgt += __shfl_xor(sgt, m);
        float tau = (sgt - 1.0f) / fmaxf(kf, 1.0f);
        if (tid < 32) alpha_sh[tid] = fmaxf(z - tau, 0.0f);
    }
    __syncthreads();

    if (tid < 256) {   // h_neigh
        float hn = 0.0f;
        #pragma unroll
        for (int mt = 0; mt < 2; mt++)
            #pragma unroll
            for (int r = 0; r < 4; r++)
                hn += alpha_sh[mt * 16 + q * 4 + r] * mval[mt][r];
        hn += __shfl_xor(hn, 16);
        hn += __shfl_xor(hn, 32);
        if (q == 0) vbuf[64 + u16] = hn;
    }
    __syncthreads();

    if (tid < 256) {   // final matvec, in-wave 4-way reduction (no part_sh)
        int u = tid >> 2, kq = tid & 3;
        bf16x8 wv0 = ld8v(node_W, (long)u * 128 + kq * 32, isb);
        bf16x8 wv1 = ld8v(node_W, (long)u * 128 + kq * 32 + 8, isb);
        bf16x8 wv2 = ld8v(node_W, (long)u * 128 + kq * 32 + 16, isb);
        bf16x8 wv3 = ld8v(node_W, (long)u * 128 + kq * 32 + 24, isb);
        float acc = 0.0f;
        #pragma unroll
        for (int i = 0; i < 8; i++) {
            acc += (float)wv0[i] * vbuf[kq * 32 + i];
            acc += (float)wv1[i] * vbuf[kq * 32 + 8 + i];
            acc += (float)wv2[i] * vbuf[kq * 32 + 16 + i];
            acc += (float)wv3[i] * vbuf[kq * 32 + 24 + i];
        }
        acc += __shfl_xor(acc, 1);
        acc += __shfl_xor(acc, 2);
        if (kq == 0) {
            float s = acc + ldf(node_b, u, isb);
            float v = fmaxf(s, 0.0f);
            long o = (long)d * 64 + u;
            if (isb) ((bf16*)outp)[o] = (bf16)v;
            else     ((float*)outp)[o] = v;
        }
    }
}

extern "C" void kernel_launch(void* const* d_in, const int* in_sizes, int n_in,
                              void* d_out, int out_size, void* d_ws, size_t ws_size,
                              hipStream_t stream) {
    gtea_fused<<<N_DSTN, 512, 0, stream>>>(
        d_in[0], d_in[1], d_in[2],
        (const int*)d_in[3], (const int*)d_in[4],
        d_in[5], d_in[6], d_in[7], d_in[8],
        d_in[9], d_in[10], d_in[11], d_in[12],
        d_in[13], d_in[14], d_in[15], d_in[16],
        d_in[17], d_in[18], d_in[19],
        d_in[20], d_in[21],
        d_out);
}

// Round 2
// 714.472 us; speedup vs baseline: 1.0948x; 1.0655x over previous
//
#include <hip/hip_runtime.h>

typedef __bf16 bf16;
typedef __bf16 bf16x8 __attribute__((ext_vector_type(8)));
typedef float f32x4 __attribute__((ext_vector_type(4)));

#define N_DSTN 8192
#define TT 16
#define HROW 72            // shorts per h row (64 + 8 pad); 144B row keeps 16B align for b128
#define HBUF (32 * HROW)   // one parity buffer, in shorts

// ---- workspace layout (bytes) ----
#define WS_WHH  0          // bf16 [2][256][64]  pre-scaled
#define WS_WIH  65536      // bf16 [2][256][16]  pre-scaled
#define WS_BIAS 81920      // f32  [2][256]      (bih+bhh)*gs
#define WS_EW   83968      // bf16 [64][128]
#define WS_NW   100352     // bf16 [64][128]
#define WS_EB   116736     // f32  [64]
#define WS_NB   116992     // f32  [64]
#define WS_ATTN 117248     // f32  [64]
#define WS_T2W  117504     // f32  [8]
#define WS_T2B  117536     // f32  [8]

__device__ __forceinline__ f32x4 MFMA(bf16x8 a, bf16x8 b, f32x4 c) {
    return __builtin_amdgcn_mfma_f32_16x16x32_bf16(a, b, c, 0, 0, 0);
}
__device__ __forceinline__ float ldf(const void* p, long i, bool isb) {
    return isb ? (float)((const bf16*)p)[i] : ((const float*)p)[i];
}
__device__ __forceinline__ bf16x8 zero8() {
    bf16x8 z;
    #pragma unroll
    for (int i = 0; i < 8; i++) z[i] = (bf16)0.0f;
    return z;
}
// 8 consecutive elements as bf16x8; i must be a multiple of 4
__device__ __forceinline__ bf16x8 ld8v(const void* p, long i, bool isb) {
    if (isb) {
        return *reinterpret_cast<const bf16x8*>((const bf16*)p + i);
    } else {
        const float* f = (const float*)p + i;
        float4 u = *reinterpret_cast<const float4*>(f);
        float4 v = *reinterpret_cast<const float4*>(f + 4);
        bf16x8 r;
        r[0] = (bf16)u.x; r[1] = (bf16)u.y; r[2] = (bf16)u.z; r[3] = (bf16)u.w;
        r[4] = (bf16)v.x; r[5] = (bf16)v.y; r[6] = (bf16)v.z; r[7] = (bf16)v.w;
        return r;
    }
}

// ---------------- prep: convert/scale all params into workspace ----------------
extern "C" __global__ void gtea_prep(const void* __restrict__ e_times,
                                     const void* __restrict__ t2v_w,
                                     const void* __restrict__ t2v_b,
                                     const void* __restrict__ t2v_w0,
                                     const void* __restrict__ t2v_b0,
                                     const void* __restrict__ Wih_e,
                                     const void* __restrict__ Whh_e,
                                     const void* __restrict__ bih_e,
                                     const void* __restrict__ bhh_e,
                                     const void* __restrict__ Wih_a,
                                     const void* __restrict__ Whh_a,
                                     const void* __restrict__ bih_a,
                                     const void* __restrict__ bhh_a,
                                     const void* __restrict__ attn_w,
                                     const void* __restrict__ edge_out_W,
                                     const void* __restrict__ edge_out_b,
                                     const void* __restrict__ node_W,
                                     const void* __restrict__ node_b,
                                     void* __restrict__ ws)
{
    __shared__ int isb_s;
    const int tid = threadIdx.x;
    if (tid < 64) {
        const unsigned short* u = (const unsigned short*)e_times;
        unsigned short a = u[tid * 2], b = u[tid * 2 + 1];
        bool ok = (a <= 0x3F80u) && (b <= 0x3F80u);
        unsigned long long m = __ballot(ok);
        if (tid == 0) isb_s = (m == ~0ULL) ? 1 : 0;
    }
    __syncthreads();
    const bool isb = (isb_s != 0);
    char* wsb = (char*)ws;
    const int gstep = blockDim.x * gridDim.x;
    const int g0 = blockIdx.x * blockDim.x + tid;

    // Whh scaled: [2][256][64]
    for (int i = g0; i < 2 * 256 * 64; i += gstep) {
        int Lw = i >> 14, rem = i & 16383, n = rem >> 6;
        const void* W = Lw ? Whh_a : Whh_e;
        float gs = ((n >> 6) == 2) ? 2.88539008f : -1.44269504f;
        ((bf16*)(wsb + WS_WHH))[i] = (bf16)(ldf(W, rem, isb) * gs);
    }
    // Wih scaled: [2][256][16]
    for (int i = g0; i < 2 * 256 * 16; i += gstep) {
        int Lw = i >> 12, rem = i & 4095, n = rem >> 4;
        const void* W = Lw ? Wih_a : Wih_e;
        float gs = ((n >> 6) == 2) ? 2.88539008f : -1.44269504f;
        ((bf16*)(wsb + WS_WIH))[i] = (bf16)(ldf(W, rem, isb) * gs);
    }
    // bias scaled: [2][256]
    for (int i = g0; i < 2 * 256; i += gstep) {
        int Lw = i >> 8, n = i & 255;
        const void* bi = Lw ? bih_a : bih_e;
        const void* bh = Lw ? bhh_a : bhh_e;
        float gs = ((n >> 6) == 2) ? 2.88539008f : -1.44269504f;
        ((float*)(wsb + WS_BIAS))[i] = (ldf(bi, n, isb) + ldf(bh, n, isb)) * gs;
    }
    // edge_out_W / node_W → bf16
    for (int i = g0; i < 64 * 128; i += gstep) {
        ((bf16*)(wsb + WS_EW))[i] = (bf16)ldf(edge_out_W, i, isb);
        ((bf16*)(wsb + WS_NW))[i] = (bf16)ldf(node_W, i, isb);
    }
    for (int i = g0; i < 64; i += gstep) {
        ((float*)(wsb + WS_EB))[i]   = ldf(edge_out_b, i, isb);
        ((float*)(wsb + WS_NB))[i]   = ldf(node_b, i, isb);
        ((float*)(wsb + WS_ATTN))[i] = ldf(attn_w, i, isb);
    }
    if (g0 < 7) {
        ((float*)(wsb + WS_T2W))[g0] = ldf(t2v_w, g0, isb);
        ((float*)(wsb + WS_T2B))[g0] = ldf(t2v_b, g0, isb);
    }
    if (g0 == 7) {
        ((float*)(wsb + WS_T2W))[7] = ldf(t2v_w0, 0, isb);
        ((float*)(wsb + WS_T2B))[7] = ldf(t2v_b0, 0, isb);
    }
}

// ---------------- main fused kernel ----------------
extern "C" __global__ void __launch_bounds__(512, 4)
gtea_fused(const void* __restrict__ node_features,
           const void* __restrict__ edge_feats,
           const void* __restrict__ e_times,
           const int*  __restrict__ e_len,
           const int*  __restrict__ edge_src,
           const void* __restrict__ ws,
           void* __restrict__ outp)
{
    // LDS total ≈ 36.2 KB → 4 blocks/CU (= 32-wave/CU cap) resource-legal with margin
    __shared__ __align__(16) bf16 habuf[2][2][HBUF];   // [L][parity]  18432 B
    __shared__ __align__(16) bf16 featb[TT * 32 * 8];  // 8192 B
    __shared__ __align__(16) bf16 tb[TT * 32 * 8];     // 8192 B
    __shared__ float t2w[8], t2b[8];
    __shared__ float attn_f[64];
    __shared__ float vbuf[128];
    __shared__ float scores_sh[32], alpha_sh[32];
    __shared__ int   lens_sh[32], idx_sh[32];
    __shared__ int   isb_sh;

    const int tid = threadIdx.x;
    const int w   = tid >> 6;
    const int l   = tid & 63;
    const int l15 = l & 15;
    const int q   = l >> 4;
    const int L   = w >> 2;          // 0: lstm_e, 1: lstm_a
    const int w4  = w & 3;
    const int u16 = w4 * 16 + l15;

    const int d  = blockIdx.x;
    const int e0 = d * 32;
    const char* wsb = (const char*)ws;

    // ---- dtype sniff ----
    if (tid < 64) {
        const unsigned short* u = (const unsigned short*)e_times;
        unsigned short a = u[tid * 2], b = u[tid * 2 + 1];
        bool ok = (a <= 0x3F80u) && (b <= 0x3F80u);
        unsigned long long m = __ballot(ok);
        if (tid == 0) isb_sh = (m == ~0ULL) ? 1 : 0;
    }
    // ---- in-wave length sort (wave 0) ----
    if (tid < 32) {
        int lj = e_len[e0 + tid];
        int rank = 0;
        for (int i = 0; i < 32; i++) {
            int li = __shfl(lj, i);
            rank += (li > lj) || (li == lj && i < tid);
        }
        int mt = rank >> 4, kp = rank & 15;
        int slot = mt * 16 + (kp & 3) * 4 + (kp >> 2);
        idx_sh[slot]  = tid;
        lens_sh[slot] = lj;
    }
    __syncthreads();
    const bool isb = (isb_sh != 0);

    // ---- S0: params from ws, h_dst, habuf parity-0 zero ----
    if (tid < 8)  { t2w[tid] = ((const float*)(wsb + WS_T2W))[tid];
                    t2b[tid] = ((const float*)(wsb + WS_T2B))[tid]; }
    if (tid < 64) attn_f[tid] = ((const float*)(wsb + WS_ATTN))[tid];
    if (tid < 64) vbuf[tid] = ldf(node_features, (long)d * 64 + tid, isb);
    {
        // zero only parity 0 of each L (parity 1 is fully written at t=0 before read)
        unsigned int* hz = reinterpret_cast<unsigned int*>(&habuf[0][0][0]);
        for (int i = tid; i < HBUF / 2; i += 512) { hz[i] = 0u; hz[i + HBUF] = 0u; }
    }
    __syncthreads();

    // ---- S2: edge staging + weights from ws ----
    int gm0[4], gm1[4];
    #pragma unroll
    for (int r = 0; r < 4; r++) {
        gm0[r] = __builtin_amdgcn_readfirstlane(lens_sh[r]);
        gm1[r] = __builtin_amdgcn_readfirstlane(lens_sh[16 + r]);
    }
    const int tmax = gm0[0], mtmax1 = gm1[0];

    unsigned lp = 0;
    #pragma unroll
    for (int mt = 0; mt < 2; mt++)
        #pragma unroll
        for (int r = 0; r < 4; r++)
            lp |= (unsigned)(lens_sh[mt * 16 + q * 4 + r] - 1) << ((mt * 4 + r) * 4);

    {
        int s = tid >> 4, t = tid & 15;
        int j = idx_sh[s];
        long base = ((long)(e0 + j) * TT + t) * 8;
        *reinterpret_cast<bf16x8*>(&featb[(t * 32 + s) * 8]) = ld8v(edge_feats, base, isb);
        float tau = ldf(e_times, (long)(e0 + j) * TT + t, isb);
        bf16x8 te;
        #pragma unroll
        for (int i = 0; i < 7; i++) te[i] = (bf16)__sinf(tau * t2w[i] + t2b[i]);
        te[7] = (bf16)(tau * t2w[7] + t2b[7]);
        *reinterpret_cast<bf16x8*>(&tb[(t * 32 + s) * 8]) = te;
    }

    const bf16*  wWhh  = (const bf16*)(wsb + WS_WHH) + (long)L * 256 * 64;
    const bf16*  wWih  = (const bf16*)(wsb + WS_WIH) + (long)L * 256 * 16;
    const float* wBias = (const float*)(wsb + WS_BIAS) + L * 256;
    bf16x8 Bh[4][2], Bx[4];
    float  bias[4];
    #pragma unroll
    for (int j = 0; j < 4; j++) {
        int n = 64 * j + u16;
        Bh[j][0] = *reinterpret_cast<const bf16x8*>(wWhh + (long)n * 64 + q * 8);
        Bh[j][1] = *reinterpret_cast<const bf16x8*>(wWhh + (long)n * 64 + 32 + q * 8);
        Bx[j] = (q < 2) ? *reinterpret_cast<const bf16x8*>(wWih + (long)n * 16 + q * 8) : zero8();
        bias[j] = wBias[n];
    }

    float c[2][4];
    #pragma unroll
    for (int mt = 0; mt < 2; mt++)
        #pragma unroll
        for (int r = 0; r < 4; r++) c[mt][r] = 0.0f;

    __syncthreads();

    // ---- recurrent loop: double-buffered h, 1 barrier/step ----
    bf16* hb_base = &habuf[L][0][0];
    const int rd_off = l15 * HROW + q * 8;
    const int wr_off = (q * 4) * HROW + u16;

    for (int t = 0; t < tmax; t++) {
        const bf16* hbR = hb_base + (t & 1) * HBUF;
        bf16*       hbW = hb_base + ((t + 1) & 1) * HBUF;

        auto do_mt = [&](int mt) {
            const bf16* hr = hbR + mt * (16 * HROW) + rd_off;
            bf16x8 ah0 = *reinterpret_cast<const bf16x8*>(hr);
            bf16x8 ah1 = *reinterpret_cast<const bf16x8*>(hr + 32);
            bf16x8 xa;
            if (q < 2) {
                const bf16* xp = (q == 0 ? featb : tb) + (t * 32 + mt * 16 + l15) * 8;
                xa = *reinterpret_cast<const bf16x8*>(xp);
            } else {
                xa = zero8();
            }
            f32x4 D[4];
            #pragma unroll
            for (int j = 0; j < 4; j++) {
                f32x4 acc = {bias[j], bias[j], bias[j], bias[j]};
                acc = MFMA(ah0, Bh[j][0], acc);
                acc = MFMA(ah1, Bh[j][1], acc);
                acc = MFMA(xa,  Bx[j],    acc);
                D[j] = acc;
            }
            bf16* hw = hbW + mt * (16 * HROW) + wr_off;
            #pragma unroll
            for (int r = 0; r < 4; r++) {
                int gmax = mt ? gm1[r] : gm0[r];
                if (t < gmax) {
                    int lm1 = (int)((lp >> ((mt * 4 + r) * 4)) & 15u);
                    if (t <= lm1) {
                        // gates pre-scaled: gi,gf,go = -x/ln2 ; gg = +2x/ln2
                        float gi = D[0][r], gf = D[1][r];
                        float gg = D[2][r], go = D[3][r];
                        float ei = __builtin_amdgcn_exp2f(gi);
                        float ef = __builtin_amdgcn_exp2f(gf);
                        float eg = __builtin_amdgcn_exp2f(gg);
                        float di = 1.0f + ei, dfv = 1.0f + ef, dg = 1.0f + eg;
                        float m1 = di * dg;
                        float R1 = __builtin_amdgcn_rcpf(m1 * dfv);
                        float cn = (m1 * R1) * c[mt][r] + (eg - 1.0f) * (dfv * R1);
                        c[mt][r] = cn;
                        float eo = __builtin_amdgcn_exp2f(go);
                        float ec = __builtin_amdgcn_exp2f(2.88539008f * cn);
                        float R2 = __builtin_amdgcn_rcpf((1.0f + eo) * (1.0f + ec));
                        float hn = (ec - 1.0f) * R2;
                        hw[r * HROW] = (bf16)hn;
                    }
                }
            }
        };
        do_mt(0);
        if (t < mtmax1) do_mt(1);
        __syncthreads();
    }

    // ---- epilogue ----
    if (tid < 256) {   // attention scores
        int s = tid >> 3, c8 = tid & 7;
        const bf16* ha = &habuf[1][lens_sh[s] & 1][s * HROW];
        float p = 0.0f;
        #pragma unroll
        for (int i = 0; i < 8; i++)
            p += (float)ha[c8 * 8 + i] * attn_f[c8 * 8 + i];
        p += __shfl_xor(p, 1);
        p += __shfl_xor(p, 2);
        p += __shfl_xor(p, 4);
        if (c8 == 0) scores_sh[s] = (p > 0.0f) ? p : 0.01f * p;
    }
    float mval[2][4];
    if (tid < 256) {   // m = relu([h_src | h_e] @ edge_out_W^T + b)
        const bf16* wEW = (const bf16*)(wsb + WS_EW);
        bf16x8 Bw[4];
        #pragma unroll
        for (int ks = 0; ks < 4; ks++)
            Bw[ks] = *reinterpret_cast<const bf16x8*>(wEW + (long)u16 * 128 + ks * 32 + q * 8);
        float mb = ((const float*)(wsb + WS_EB))[u16];
        #pragma unroll
        for (int mt = 0; mt < 2; mt++) {
            int s = mt * 16 + l15;
            int src = edge_src[e0 + idx_sh[s]];
            bf16x8 a0 = ld8v(node_features, (long)src * 64 + q * 8, isb);
            bf16x8 a1 = ld8v(node_features, (long)src * 64 + 32 + q * 8, isb);
            const bf16* he = &habuf[0][lens_sh[s] & 1][s * HROW];
            bf16x8 a2 = *reinterpret_cast<const bf16x8*>(he + q * 8);
            bf16x8 a3 = *reinterpret_cast<const bf16x8*>(he + 32 + q * 8);
            f32x4 acc = {mb, mb, mb, mb};
            acc = MFMA(a0, Bw[0], acc);
            acc = MFMA(a1, Bw[1], acc);
            acc = MFMA(a2, Bw[2], acc);
            acc = MFMA(a3, Bw[3], acc);
            #pragma unroll
            for (int r = 0; r < 4; r++) mval[mt][r] = fmaxf(acc[r], 0.0f);
        }
    }
    __syncthreads();

    if (tid < 64) {   // sparsemax (reference-exact)
        float z = (tid < 32) ? scores_sh[tid] : -3.0e38f;
        float zm = z;
        #pragma unroll
        for (int m = 32; m >= 1; m >>= 1) zm = fmaxf(zm, __shfl_xor(zm, m));
        z -= zm;
        int cnt = 0; float sb = 0.0f;
        for (int i = 0; i < 32; i++) {
            float zi = __shfl(z, i);
            bool before = (zi > z) || (zi == z && i < tid);
            if (before) { cnt++; sb += zi; }
        }
        float r = (float)(cnt + 1);
        float S = sb + z;
        bool isgt = (tid < 32) && (1.0f + r * z > S);
        float kf  = isgt ? r : 0.0f;
        float sgt = isgt ? z : 0.0f;
        #pragma unroll
        for (int m = 32; m >= 1; m >>= 1) kf = fmaxf(kf, __shfl_xor(kf, m));
        #pragma unroll
        for (int m = 32; m >= 1; m >>= 1) sgt += __shfl_xor(sgt, m);
        float tau = (sgt - 1.0f) / fmaxf(kf, 1.0f);
        if (tid < 32) alpha_sh[tid] = fmaxf(z - tau, 0.0f);
    }
    __syncthreads();

    if (tid < 256) {   // h_neigh
        float hn = 0.0f;
        #pragma unroll
        for (int mt = 0; mt < 2; mt++)
            #pragma unroll
            for (int r = 0; r < 4; r++)
                hn += alpha_sh[mt * 16 + q * 4 + r] * mval[mt][r];
        hn += __shfl_xor(hn, 16);
        hn += __shfl_xor(hn, 32);
        if (q == 0) vbuf[64 + u16] = hn;
    }
    __syncthreads();

    if (tid < 256) {   // final matvec, in-wave 4-way reduction
        int u = tid >> 2, kq = tid & 3;
        const bf16* wNW = (const bf16*)(wsb + WS_NW);
        bf16x8 wv0 = *reinterpret_cast<const bf16x8*>(wNW + (long)u * 128 + kq * 32);
        bf16x8 wv1 = *reinterpret_cast<const bf16x8*>(wNW + (long)u * 128 + kq * 32 + 8);
        bf16x8 wv2 = *reinterpret_cast<const bf16x8*>(wNW + (long)u * 128 + kq * 32 + 16);
        bf16x8 wv3 = *reinterpret_cast<const bf16x8*>(wNW + (long)u * 128 + kq * 32 + 24);
        float acc = 0.0f;
        #pragma unroll
        for (int i = 0; i < 8; i++) {
            acc += (float)wv0[i] * vbuf[kq * 32 + i];
            acc += (float)wv1[i] * vbuf[kq * 32 + 8 + i];
            acc += (float)wv2[i] * vbuf[kq * 32 + 16 + i];
            acc += (float)wv3[i] * vbuf[kq * 32 + 24 + i];
        }
        acc += __shfl_xor(acc, 1);
        acc += __shfl_xor(acc, 2);
        if (kq == 0) {
            float s = acc + ((const float*)(wsb + WS_NB))[u];
            float v = fmaxf(s, 0.0f);
            long o = (long)d * 64 + u;
            if (isb) ((bf16*)outp)[o] = (bf16)v;
            else     ((float*)outp)[o] = v;
        }
    }
}

extern "C" void kernel_launch(void* const* d_in, const int* in_sizes, int n_in,
                              void* d_out, int out_size, void* d_ws, size_t ws_size,
                              hipStream_t stream) {
    gtea_prep<<<32, 256, 0, stream>>>(
        d_in[2],                                  // e_times (dtype sniff)
        d_in[5], d_in[6], d_in[7], d_in[8],       // t2v
        d_in[9], d_in[10], d_in[11], d_in[12],    // lstm_e
        d_in[13], d_in[14], d_in[15], d_in[16],   // lstm_a
        d_in[17], d_in[18], d_in[19],             // attn_w, edge_out_W, edge_out_b
        d_in[20], d_in[21],                       // node_W, node_b
        d_ws);
    gtea_fused<<<N_DSTN, 512, 0, stream>>>(
        d_in[0], d_in[1], d_in[2],
        (const int*)d_in[3], (const int*)d_in[4],
        d_ws, d_out);
}